// Round 6
// baseline (102.243 us; speedup 1.0000x reference)
//
#include <hip/hip_runtime.h>
#include <hip/hip_bf16.h>

// B=32, D=128, H=256, O=10.
// s = 1-tanh(W1^T x + b1)^2, u = -2 z s, P = W1^T W1 (HxH).
// Rank-10 structure (M = W2 W2^T):
//   sw2[g,o] = s_g W2[g,o];
//   E = W1^T (W1 sw2) = P sw2          <-- round-6: use helpers' P, kills F1
//   y_o = sum_h W2[h,o] u_h w_h^2  (w = W1^T v)
//   m_g = sum_o sw2[g,o] y_o;  a_un = W1 m   (== F1 y, rearranged)
//   C[o,p] = sum_g sw2[g,o] E[g,p] (10x10), CW = C W2^T
//   F^2 = 2 sum u_h u_h' (P^2 o Q + P o R o R^T)  (same band pair-set as all
//     verified rounds: column t2 sums rows (t2>>6)*64 + [0,64))
//   a_i = -a_un[i]/((F+1e-6)(||v||+1e-6))
// Round-6: 1024-thread blocks (16 waves = 4/SIMD; round-5 was still ~75%
// latency-stalled at 2/SIMD). Phases split 4-8 ways; cross-wave partials
// combined with LDS atomicAdd (ds_add_f32, fp32 reorder only). Helpers: 64
// blocks x 1024 thr, 4 P rows each. Fence-free relaxed-atomic handoff kept
// verbatim from rounds 4/5 (sc1 stores -> coherent point; RELAXED flag after
// vmcnt-drain; RELAXED spin; plain consumer loads). Spin moved before E
// (E needs P now); helpers run concurrently and finish under proj phase.

#define NB 32
#define NH 64       // helper blocks
#define OP 0        // ws: P [h*256+g], 65536 floats

__device__ int g_pdone = 0;
__device__ int g_bdone = 0;

template<int BF> __device__ __forceinline__ float ld(const void* p, int i) {
  if constexpr (BF) return __bfloat162float(((const __hip_bfloat16*)p)[i]);
  else return ((const float*)p)[i];
}
template<int BF> __device__ __forceinline__ void st(void* p, int i, float v) {
  if constexpr (BF) ((__hip_bfloat16*)p)[i] = __float2bfloat16(v);
  else ((float*)p)[i] = v;
}
__device__ __forceinline__ float b2f(unsigned short u) {
  return __uint_as_float(((unsigned int)u) << 16);
}
// 8 consecutive elements, idx %8==0 (BF path: one 16B uint4 load)
template<int BF> __device__ __forceinline__ void ld8v(const void* p, int i, float* o) {
  if constexpr (BF) {
    uint4 u = *(const uint4*)((const unsigned short*)p + i);
    o[0] = b2f((unsigned short)(u.x & 0xffff)); o[1] = b2f((unsigned short)(u.x >> 16));
    o[2] = b2f((unsigned short)(u.y & 0xffff)); o[3] = b2f((unsigned short)(u.y >> 16));
    o[4] = b2f((unsigned short)(u.z & 0xffff)); o[5] = b2f((unsigned short)(u.z >> 16));
    o[6] = b2f((unsigned short)(u.w & 0xffff)); o[7] = b2f((unsigned short)(u.w >> 16));
  } else {
    float4 a = *(const float4*)((const float*)p + i);
    float4 b = *(const float4*)((const float*)p + i + 4);
    o[0]=a.x; o[1]=a.y; o[2]=a.z; o[3]=a.w; o[4]=b.x; o[5]=b.y; o[6]=b.z; o[7]=b.w;
  }
}

// dtype sniff: view first 256 half-words of state_batch as bf16. fp32 storage
// puts random-exponent garbage in the low halves -> some |v|>1000 w.p. ~1.
__device__ __forceinline__ int blocksniff(const void* sb, int* sh) {
  if (threadIdx.x == 0) *sh = 0;
  __syncthreads();
  float v = fabsf(__bfloat162float(((const __hip_bfloat16*)sb)[threadIdx.x & 255]));
  if (!(v < 1000.0f)) atomicOr(sh, 1);
  __syncthreads();
  return (*sh == 0) ? 1 : 0;
}

// LDS carve (floats), total 14784 = 57.8 KB (<64KB static cap)
#define LXS   0       // 128
#define LVS   128     // 128
#define LW2   256     // 2560 raw W2 (stride 10)
#define LYS   2816    // 16: [0..9]=y, [10]=||v||
#define LRED  2832    // 192: 16 waves * 12 (y phase rows 0..3; F^2 uses [0..15])
#define LHW   3024    // 2048: proj partials [ch4][t2][2]
#define LSW2  5072    // 3072: sw2 stride 12
#define LEL   8144    // 3072: E (atomic accum) + u in slot 10
#define LW2P  11216   // 3072: padded W2 stride 12
#define LCL   14288   // 112: C (atomic accum, 100 used)
#define LM    14400   // 256: m_g
#define LAUN  14656   // 128: a_un (atomic accum)
#define LTOT  14784

template<int BF>
__device__ void fk_body(const void* tin, const void* sbin, const void* x0in,
                        const void* x1in, const void* W1in, const void* b1in,
                        const void* W2in, void* out, float* ws, float* sm) {
  int bid = blockIdx.x, t = threadIdx.x;
  if (bid >= NB) {
    // ---- helper block: 4 P rows (row0..row0+3) ----
    int row0 = (bid - NB) * 4;
    if (t < 512) {               // stage 4 W1 columns
      int qq = t >> 7, d = t & 127;
      sm[qq * 128 + d] = ld<BF>(W1in, d * 256 + row0 + qq);
    }
    __syncthreads();
    int q = t >> 8, c = t & 255;
    const float* ch = &sm[q * 128];
    float pacc = 0.f;
    for (int d = 0; d < 128; d += 4) {
      float4 c4 = *(const float4*)&ch[d];
      pacc += c4.x * ld<BF>(W1in, (d + 0) * 256 + c);
      pacc += c4.y * ld<BF>(W1in, (d + 1) * 256 + c);
      pacc += c4.z * ld<BF>(W1in, (d + 2) * 256 + c);
      pacc += c4.w * ld<BF>(W1in, (d + 3) * 256 + c);
    }
    // coherent (sc1) store: visible at device coherent point, no dirty L2 line
    __hip_atomic_store(&ws[OP + (row0 + q) * 256 + c], pacc,
                       __ATOMIC_RELAXED, __HIP_MEMORY_SCOPE_AGENT);
    __syncthreads();   // drains vmcnt(0): all 1024 coherent stores ack'd
    if (t == 0)
      __hip_atomic_fetch_add(&g_pdone, 1, __ATOMIC_RELAXED, __HIP_MEMORY_SCOPE_AGENT);
    return;
  }
  // ---- batch block b (1024 threads, 16 waves) ----
  int b = bid;
  int t2  = t & 255;         // h / column index (4 replicas)
  int ch4 = t >> 8;          // 0..3 chunk
  int w   = t >> 6;          // wave 0..15
  float tt = ld<BF>(tin, 0);
  float window = 4.f * tt * (1.f - tt);
  // P0: inputs, W2, zero-init accum regions
  if (t < 128) {
    float dev = ld<BF>(sbin, b * 128 + t);
    float v   = ld<BF>(sbin, (NB + b) * 128 + t);
    float x0v = ld<BF>(x0in, b * 128 + t);
    float x1v = ld<BF>(x1in, b * 128 + t);
    sm[LXS + t] = x0v + tt * (x1v - x0v) + window * dev;
    sm[LVS + t] = v;
    sm[LAUN + t] = 0.f;
  }
  for (int i = t; i < 2560; i += 1024) sm[LW2 + i] = ld<BF>(W2in, i);
  for (int i = t; i < 3072; i += 1024) sm[LEL + i] = 0.f;
  if (t < 100) sm[LCL + t] = 0.f;
  __syncthreads();                                   // (1)
  // P1: proj partials over own 32-d chunk (coalesced column reads); W2P copy
  float hp = (ch4 == 0) ? ld<BF>(b1in, t2) : 0.f, wp = 0.f;
  {
    int d0 = ch4 * 32;
    for (int d = d0; d < d0 + 32; d += 4) {
      float4 xv = *(const float4*)&sm[LXS + d];
      float4 vv = *(const float4*)&sm[LVS + d];
      float w0 = ld<BF>(W1in, (d + 0) * 256 + t2);
      float w1 = ld<BF>(W1in, (d + 1) * 256 + t2);
      float w2 = ld<BF>(W1in, (d + 2) * 256 + t2);
      float w3 = ld<BF>(W1in, (d + 3) * 256 + t2);
      hp += w0 * xv.x + w1 * xv.y + w2 * xv.z + w3 * xv.w;
      wp += w0 * vv.x + w1 * vv.y + w2 * vv.z + w3 * vv.w;
    }
  }
  sm[LHW + (ch4 * 256 + t2) * 2]     = hp;
  sm[LHW + (ch4 * 256 + t2) * 2 + 1] = wp;
  float w2r[10];
  #pragma unroll
  for (int o = 0; o < 10; ++o) w2r[o] = sm[LW2 + t2 * 10 + o];
  for (int i = t; i < 3072; i += 1024) {
    int rr = i / 12, cc = i - rr * 12;
    sm[LW2P + i] = (cc < 10) ? sm[LW2 + rr * 10 + cc] : 0.f;
  }
  __syncthreads();                                   // (2)
  // P2: t<256: combine proj halves, activation, sw2, y/||v|| wave-reduce
  float ug = 0.f;
  if (t < 256) {
    float hacc = sm[LHW + t2 * 2]           + sm[LHW + (256 + t2) * 2]
               + sm[LHW + (512 + t2) * 2]   + sm[LHW + (768 + t2) * 2];
    float wacc = sm[LHW + t2 * 2 + 1]       + sm[LHW + (256 + t2) * 2 + 1]
               + sm[LHW + (512 + t2) * 2 + 1] + sm[LHW + (768 + t2) * 2 + 1];
    float z  = tanhf(hacc);
    float sg = 1.f - z * z;
    ug = -2.f * z * sg;
    #pragma unroll
    for (int o = 0; o < 10; ++o) sm[LSW2 + t2 * 12 + o] = sg * w2r[o];
    float cval = ug * wacc * wacc;
    float rv[11];
    #pragma unroll
    for (int o = 0; o < 10; ++o) rv[o] = cval * w2r[o];
    rv[10] = (t < 128) ? sm[LVS + t] * sm[LVS + t] : 0.f;
    #pragma unroll
    for (int o = 0; o < 11; ++o) {
      float v = rv[o];
      #pragma unroll
      for (int m = 32; m > 0; m >>= 1) v += __shfl_xor(v, m);
      if ((t & 63) == 0) sm[LRED + w * 12 + o] = v;
    }
  }
  __syncthreads();                                   // (3)
  // P3: y/||v|| combine; spin for P (RELAXED, no cache-maintenance)
  if (t < 11) {
    float s = sm[LRED + t] + sm[LRED + 12 + t] + sm[LRED + 24 + t] + sm[LRED + 36 + t];
    if (t < 10) sm[LYS + t] = s;
    else        sm[LYS + 10] = sqrtf(s);
  }
  if (t == 0) {
    while (__hip_atomic_load(&g_pdone, __ATOMIC_RELAXED, __HIP_MEMORY_SCOPE_AGENT) < NH)
      __builtin_amdgcn_s_sleep(2);
  }
  __syncthreads();                                   // (4)
  // P4: E[t2,:] += sum_{g' in chunk} P[g',t2] sw2[g',:]  (P symmetric; 
  // coalesced fp32 loads over t2, sw2 rows wave-broadcast). Also m on t<256.
  if (t < 256) {
    float m = 0.f;
    #pragma unroll
    for (int o = 0; o < 10; ++o) m += sm[LSW2 + t2 * 12 + o] * sm[LYS + o];
    sm[LM + t2] = m;
  }
  {
    float eacc[10];
    #pragma unroll
    for (int o = 0; o < 10; ++o) eacc[o] = 0.f;
    int g0 = ch4 * 64;
    for (int gg = 0; gg < 64; gg += 16) {
      float ph[16];
      #pragma unroll
      for (int j = 0; j < 16; ++j)
        ph[j] = ws[OP + (g0 + gg + j) * 256 + t2];   // 16 loads in flight
      #pragma unroll
      for (int j = 0; j < 16; ++j) {
        const float* sp = &sm[LSW2 + (g0 + gg + j) * 12];
        float4 s0 = *(const float4*)sp;
        float4 s1 = *(const float4*)(sp + 4);
        float2 s2 = *(const float2*)(sp + 8);
        float p = ph[j];
        eacc[0] += p * s0.x; eacc[1] += p * s0.y; eacc[2] += p * s0.z; eacc[3] += p * s0.w;
        eacc[4] += p * s1.x; eacc[5] += p * s1.y; eacc[6] += p * s1.z; eacc[7] += p * s1.w;
        eacc[8] += p * s2.x; eacc[9] += p * s2.y;
      }
    }
    #pragma unroll
    for (int o = 0; o < 10; ++o) atomicAdd(&sm[LEL + t2 * 12 + o], eacc[o]);
  }
  __syncthreads();                                   // (5) E final; m ready
  // P5: u into E slot 10; a_un = W1 m (8-way g-split); C (8 chunks x 100)
  if (t < 256) sm[LEL + t2 * 12 + 10] = ug;
  {
    int r = t & 127, ch8 = t >> 7;
    int ga0 = ch8 * 32;
    float ap = 0.f;
    for (int g = ga0; g < ga0 + 32; g += 8) {
      float wv[8];
      ld8v<BF>(W1in, r * 256 + g, wv);
      ap += wv[0] * sm[LM + g]     + wv[1] * sm[LM + g + 1]
          + wv[2] * sm[LM + g + 2] + wv[3] * sm[LM + g + 3]
          + wv[4] * sm[LM + g + 4] + wv[5] * sm[LM + g + 5]
          + wv[6] * sm[LM + g + 6] + wv[7] * sm[LM + g + 7];
    }
    atomicAdd(&sm[LAUN + r], ap);
  }
  if (t < 800) {
    int chk = t / 100, idx = t - chk * 100;
    int o = idx / 10, p = idx - o * 10;
    int gc0 = chk * 32;
    float cp = 0.f;
    #pragma unroll 4
    for (int g = gc0; g < gc0 + 32; ++g)
      cp += sm[LSW2 + g * 12 + o] * sm[LEL + g * 12 + p];
    atomicAdd(&sm[LCL + idx], cp);
  }
  __syncthreads();                                   // (6)
  // P6: CW row + E row to regs; F^2 over own 16-row quarter of the band
  float cwr[10], er[10], uc;
  #pragma unroll
  for (int o = 0; o < 10; ++o) {
    float cw = 0.f;
    #pragma unroll
    for (int p = 0; p < 10; ++p) cw += sm[LCL + o * 10 + p] * w2r[p];
    cwr[o] = cw;
  }
  {
    const float* ep = &sm[LEL + t2 * 12];
    float4 e0 = *(const float4*)ep;
    float4 e1 = *(const float4*)(ep + 4);
    float4 e2 = *(const float4*)(ep + 8);
    er[0]=e0.x; er[1]=e0.y; er[2]=e0.z; er[3]=e0.w;
    er[4]=e1.x; er[5]=e1.y; er[6]=e1.z; er[7]=e1.w;
    er[8]=e2.x; er[9]=e2.y; uc = e2.z;
  }
  int band = (t2 >> 6) * 64 + ch4 * 16;
  float acc = 0.f;
  {
    float ph[16];
    #pragma unroll
    for (int j = 0; j < 16; ++j)
      ph[j] = ws[OP + (band + j) * 256 + t2];        // 16 loads in flight
    #pragma unroll
    for (int j = 0; j < 16; ++j) {
      int h = band + j;
      const float* rp = &sm[LEL + h * 12];
      float4 E0 = *(const float4*)rp;
      float4 E1 = *(const float4*)(rp + 4);
      float4 E2 = *(const float4*)(rp + 8);     // E8,E9,u,0
      const float* wpp = &sm[LW2P + h * 12];
      float4 W0 = *(const float4*)wpp;
      float4 W1v = *(const float4*)(wpp + 4);
      float4 W2v = *(const float4*)(wpp + 8);   // W8,W9,0,0
      float R = E0.x*w2r[0] + E0.y*w2r[1] + E0.z*w2r[2] + E0.w*w2r[3]
              + E1.x*w2r[4] + E1.y*w2r[5] + E1.z*w2r[6] + E1.w*w2r[7]
              + E2.x*w2r[8] + E2.y*w2r[9];
      float Rt = W0.x*er[0] + W0.y*er[1] + W0.z*er[2] + W0.w*er[3]
               + W1v.x*er[4] + W1v.y*er[5] + W1v.z*er[6] + W1v.w*er[7]
               + W2v.x*er[8] + W2v.y*er[9];
      float Qd = W0.x*cwr[0] + W0.y*cwr[1] + W0.z*cwr[2] + W0.w*cwr[3]
               + W1v.x*cwr[4] + W1v.y*cwr[5] + W1v.z*cwr[6] + W1v.w*cwr[7]
               + W2v.x*cwr[8] + W2v.y*cwr[9];
      acc += E2.z * ph[j] * (ph[j] * Qd + R * Rt);
    }
  }
  acc *= uc;
  #pragma unroll
  for (int m = 32; m > 0; m >>= 1) acc += __shfl_xor(acc, m);
  if ((t & 63) == 0) sm[LRED + w] = acc;             // LRED[0..15] (y use dead)
  __syncthreads();                                   // (7)
  float fsum = 0.f;
  #pragma unroll
  for (int i = 0; i < 16; ++i) fsum += sm[LRED + i];
  float F = sqrtf(fmaxf(2.f * fsum, 0.f));
  float denom = (F + 1e-6f) * (sm[LYS + 10] + 1e-6f);
  if (t < 128) {
    st<BF>(out, b * 128 + t, ld<BF>(sbin, (NB + b) * 128 + t));   // dev_velocity
    float dev = ld<BF>(sbin, b * 128 + t);
    float val = -sm[LAUN + t] / denom - 0.1f * dev;
    st<BF>(out, (NB + b) * 128 + t, val);
  }
  __syncthreads();                                   // (8)
  if (t == 0) {
    int old = __hip_atomic_fetch_add(&g_bdone, 1, __ATOMIC_RELAXED, __HIP_MEMORY_SCOPE_AGENT);
    if (old == NB - 1) {   // last batch block: reset flags for next launch
      __hip_atomic_store(&g_pdone, 0, __ATOMIC_RELAXED, __HIP_MEMORY_SCOPE_AGENT);
      __hip_atomic_store(&g_bdone, 0, __ATOMIC_RELAXED, __HIP_MEMORY_SCOPE_AGENT);
    }
  }
}

__global__ __launch_bounds__(1024) void FK(const void* tin, const void* sbin,
                                           const void* x0in, const void* x1in,
                                           const void* W1in, const void* b1in,
                                           const void* W2in, void* out, float* ws) {
  __shared__ int sh;
  __shared__ __align__(16) float sm[LTOT];
  int bf = blocksniff(sbin, &sh);
  if (bf) fk_body<1>(tin, sbin, x0in, x1in, W1in, b1in, W2in, out, ws, sm);
  else    fk_body<0>(tin, sbin, x0in, x1in, W1in, b1in, W2in, out, ws, sm);
}

extern "C" void kernel_launch(void* const* d_in, const int* in_sizes, int n_in,
                              void* d_out, int out_size, void* d_ws, size_t ws_size,
                              hipStream_t stream) {
  float* ws = (float*)d_ws;
  const void* tin  = d_in[0];
  const void* sbin = d_in[1];
  const void* x0in = d_in[2];
  const void* x1in = d_in[3];
  const void* W1in = d_in[4];
  const void* b1in = d_in[5];
  const void* W2in = d_in[6];
  // d_in[7] (b2) cancels in every derivative.

  FK<<<dim3(NB + NH), dim3(1024), 0, stream>>>(tin, sbin, x0in, x1in, W1in, b1in, W2in, d_out, ws);
}

// Round 7
// 100.715 us; speedup vs baseline: 1.0152x; 1.0152x over previous
//
#include <hip/hip_runtime.h>
#include <hip/hip_bf16.h>

// B=32, D=128, H=256, O=10.
// s = 1-tanh(W1^T x + b1)^2, u = -2 z s, P = W1^T W1 (HxH).
// Rank-10 structure (M = W2 W2^T):
//   sw2[g,o] = s_g W2[g,o];
//   E = W1^T (W1 sw2) = P sw2            (helpers' P reused; no F1 phase)
//   y_o = sum_h W2[h,o] u_h w_h^2  (w = W1^T v)
//   m_g = sum_o sw2[g,o] y_o;  a_un = W1 m
//   C[o,p] = sum_g sw2[g,o] E[g,p] (10x10), CW = C W2^T
//   F^2 = 2 sum u_h u_h' (P^2 o Q + P o R o R^T)  (band pair-set identical to
//     all verified rounds: column t2 sums rows (t2>>6)*64 + [0,64))
//   a_i = -a_un[i]/((F+1e-6)(||v||+1e-6))
// Round-7: round-6's algebra at round-5's geometry. Round-6 regressed because
// __launch_bounds__(1024) capped VGPR at 64 -> scratch spills in the F^2/E
// phases (counters: VGPR_Count=64, FETCH 1748KB, VALUBusy down). 512-thread
// blocks restore a 256-VGPR budget at 2 waves/SIMD (round-5 proven). Helpers:
// 128 blocks x 512 thr, 2 P rows each (round-5 verbatim). Fence-free
// relaxed-atomic handoff kept (sc1 stores -> coherent point; RELAXED flag
// after vmcnt-drain; RELAXED spin; plain consumer loads). Spin sits before
// the E phase (E needs P); helper latency hides under proj.

#define NB 32
#define NH 128      // helper blocks
#define OP 0        // ws: P [h*256+g], 65536 floats

__device__ int g_pdone = 0;
__device__ int g_bdone = 0;

template<int BF> __device__ __forceinline__ float ld(const void* p, int i) {
  if constexpr (BF) return __bfloat162float(((const __hip_bfloat16*)p)[i]);
  else return ((const float*)p)[i];
}
template<int BF> __device__ __forceinline__ void st(void* p, int i, float v) {
  if constexpr (BF) ((__hip_bfloat16*)p)[i] = __float2bfloat16(v);
  else ((float*)p)[i] = v;
}
__device__ __forceinline__ float b2f(unsigned short u) {
  return __uint_as_float(((unsigned int)u) << 16);
}
// 8 consecutive elements, idx %8==0 (BF path: one 16B uint4 load)
template<int BF> __device__ __forceinline__ void ld8v(const void* p, int i, float* o) {
  if constexpr (BF) {
    uint4 u = *(const uint4*)((const unsigned short*)p + i);
    o[0] = b2f((unsigned short)(u.x & 0xffff)); o[1] = b2f((unsigned short)(u.x >> 16));
    o[2] = b2f((unsigned short)(u.y & 0xffff)); o[3] = b2f((unsigned short)(u.y >> 16));
    o[4] = b2f((unsigned short)(u.z & 0xffff)); o[5] = b2f((unsigned short)(u.z >> 16));
    o[6] = b2f((unsigned short)(u.w & 0xffff)); o[7] = b2f((unsigned short)(u.w >> 16));
  } else {
    float4 a = *(const float4*)((const float*)p + i);
    float4 b = *(const float4*)((const float*)p + i + 4);
    o[0]=a.x; o[1]=a.y; o[2]=a.z; o[3]=a.w; o[4]=b.x; o[5]=b.y; o[6]=b.z; o[7]=b.w;
  }
}

// dtype sniff: view first 256 half-words of state_batch as bf16. fp32 storage
// puts random-exponent garbage in the low halves -> some |v|>1000 w.p. ~1.
__device__ __forceinline__ int blocksniff(const void* sb, int* sh) {
  if (threadIdx.x == 0) *sh = 0;
  __syncthreads();
  float v = fabsf(__bfloat162float(((const __hip_bfloat16*)sb)[threadIdx.x & 255]));
  if (!(v < 1000.0f)) atomicOr(sh, 1);
  __syncthreads();
  return (*sh == 0) ? 1 : 0;
}

// LDS carve (floats), total 13152 = 52.6 KB
#define LXS   0       // 128
#define LVS   128     // 128
#define LW2   256     // 2560 raw W2 (stride 10)
#define LYS   2816    // 16: [0..9]=y, [10]=||v||
#define LRED  2832    // 96: 8 waves * 12 (y phase waves 0..3; F^2 uses [0..7])
#define LHW   2928    // 512: q=1 proj partials
#define LSW2  3440    // 3072: sw2 stride 12
#define LEL   6512    // 3072: E (atomic accum) + u in slot 10
#define LW2P  9584    // 3072: padded W2 stride 12
#define LCL   12656   // 112: C (atomic accum, 100 used)
#define LM    12768   // 256: m_g
#define LAUN  13024   // 128: a_un (atomic accum)
#define LTOT  13152

template<int BF>
__device__ void fk_body(const void* tin, const void* sbin, const void* x0in,
                        const void* x1in, const void* W1in, const void* b1in,
                        const void* W2in, void* out, float* ws, float* sm) {
  int bid = blockIdx.x, t = threadIdx.x;
  if (bid >= NB) {
    // ---- helper block: 2 P rows (row0, row0+1) [round-5 verbatim] ----
    int row0 = (bid - NB) * 2;
    float* colh = sm;            // 256: two W1 columns
    if (t < 256) {
      int qq = t >> 7, d = t & 127;
      colh[qq * 128 + d] = ld<BF>(W1in, d * 256 + row0 + qq);
    }
    __syncthreads();
    int q = t >> 8, c = t & 255;
    const float* ch = &colh[q * 128];
    float pacc = 0.f;
    for (int d = 0; d < 128; d += 4) {
      float4 c4 = *(const float4*)&ch[d];
      pacc += c4.x * ld<BF>(W1in, (d + 0) * 256 + c);
      pacc += c4.y * ld<BF>(W1in, (d + 1) * 256 + c);
      pacc += c4.z * ld<BF>(W1in, (d + 2) * 256 + c);
      pacc += c4.w * ld<BF>(W1in, (d + 3) * 256 + c);
    }
    // coherent (sc1) store: visible at device coherent point, no dirty L2 line
    __hip_atomic_store(&ws[OP + (row0 + q) * 256 + c], pacc,
                       __ATOMIC_RELAXED, __HIP_MEMORY_SCOPE_AGENT);
    __syncthreads();   // drains vmcnt(0): all 512 coherent stores ack'd
    if (t == 0)
      __hip_atomic_fetch_add(&g_pdone, 1, __ATOMIC_RELAXED, __HIP_MEMORY_SCOPE_AGENT);
    return;
  }
  // ---- batch block b (512 threads, 8 waves) ----
  int b = bid;
  int t2 = t & 255;          // h / column index (2 replicas)
  int q  = t >> 8;           // 0/1 half
  int w  = t >> 6;           // wave 0..7
  float tt = ld<BF>(tin, 0);
  float window = 4.f * tt * (1.f - tt);
  // P0: inputs, W2 stage, zero accumulation regions
  if (t < 128) {
    float dev = ld<BF>(sbin, b * 128 + t);
    float v   = ld<BF>(sbin, (NB + b) * 128 + t);
    float x0v = ld<BF>(x0in, b * 128 + t);
    float x1v = ld<BF>(x1in, b * 128 + t);
    sm[LXS + t] = x0v + tt * (x1v - x0v) + window * dev;
    sm[LVS + t] = v;
    sm[LAUN + t] = 0.f;
  }
  for (int i = t; i < 2560; i += 512) sm[LW2 + i] = ld<BF>(W2in, i);
  for (int i = t; i < 3072; i += 512) sm[LEL + i] = 0.f;
  if (t < 100) sm[LCL + t] = 0.f;
  __syncthreads();                                   // (1)
  // P1: proj partials over own d-half (coalesced column reads); W2P copy
  float hp = q ? 0.f : ld<BF>(b1in, t2), wp = 0.f;
  {
    int d0 = q * 64;
    for (int d = d0; d < d0 + 64; d += 4) {
      float4 xv = *(const float4*)&sm[LXS + d];
      float4 vv = *(const float4*)&sm[LVS + d];
      float w0 = ld<BF>(W1in, (d + 0) * 256 + t2);
      float w1 = ld<BF>(W1in, (d + 1) * 256 + t2);
      float w2 = ld<BF>(W1in, (d + 2) * 256 + t2);
      float w3 = ld<BF>(W1in, (d + 3) * 256 + t2);
      hp += w0 * xv.x + w1 * xv.y + w2 * xv.z + w3 * xv.w;
      wp += w0 * vv.x + w1 * vv.y + w2 * vv.z + w3 * vv.w;
    }
  }
  if (q) { sm[LHW + t2 * 2] = hp; sm[LHW + t2 * 2 + 1] = wp; }
  float w2r[10];
  #pragma unroll
  for (int o = 0; o < 10; ++o) w2r[o] = sm[LW2 + t2 * 10 + o];
  for (int i = t; i < 3072; i += 512) {
    int rr = i / 12, cc = i - rr * 12;
    sm[LW2P + i] = (cc < 10) ? sm[LW2 + rr * 10 + cc] : 0.f;
  }
  __syncthreads();                                   // (2)
  // P2: t<256: combine halves, activation, sw2, y/||v|| wave-reduce
  float ug = 0.f;
  if (!q) {
    float hacc = hp + sm[LHW + t2 * 2];
    float wacc = wp + sm[LHW + t2 * 2 + 1];
    float z  = tanhf(hacc);
    float sg = 1.f - z * z;
    ug = -2.f * z * sg;
    #pragma unroll
    for (int o = 0; o < 10; ++o) sm[LSW2 + t2 * 12 + o] = sg * w2r[o];
    float cval = ug * wacc * wacc;
    float rv[11];
    #pragma unroll
    for (int o = 0; o < 10; ++o) rv[o] = cval * w2r[o];
    rv[10] = (t < 128) ? sm[LVS + t] * sm[LVS + t] : 0.f;
    #pragma unroll
    for (int o = 0; o < 11; ++o) {
      float v = rv[o];
      #pragma unroll
      for (int m = 32; m > 0; m >>= 1) v += __shfl_xor(v, m);
      if ((t & 63) == 0) sm[LRED + w * 12 + o] = v;
    }
  }
  __syncthreads();                                   // (3)
  // P3: y/||v|| combine; spin for P (RELAXED, no cache-maintenance ops)
  if (t < 11) {
    float s = sm[LRED + t] + sm[LRED + 12 + t] + sm[LRED + 24 + t] + sm[LRED + 36 + t];
    if (t < 10) sm[LYS + t] = s;
    else        sm[LYS + 10] = sqrtf(s);
  }
  if (t == 0) {
    while (__hip_atomic_load(&g_pdone, __ATOMIC_RELAXED, __HIP_MEMORY_SCOPE_AGENT) < NH)
      __builtin_amdgcn_s_sleep(2);
  }
  __syncthreads();                                   // (4)
  // P4: m_g (t<256); E[t2,:] = sum_g P[g,t2] sw2[g,:]  (q-split over g;
  // P loads coalesced fp32 over t2, sw2 rows wave-broadcast)
  if (t < 256) {
    float m = 0.f;
    #pragma unroll
    for (int o = 0; o < 10; ++o) m += sm[LSW2 + t2 * 12 + o] * sm[LYS + o];
    sm[LM + t2] = m;
  }
  {
    float eacc[10];
    #pragma unroll
    for (int o = 0; o < 10; ++o) eacc[o] = 0.f;
    int g0 = q * 128;
    for (int gg = 0; gg < 128; gg += 16) {
      float ph[16];
      #pragma unroll
      for (int j = 0; j < 16; ++j)
        ph[j] = ws[OP + (g0 + gg + j) * 256 + t2];   // 16 loads in flight
      #pragma unroll
      for (int j = 0; j < 16; ++j) {
        const float* sp = &sm[LSW2 + (g0 + gg + j) * 12];
        float4 s0 = *(const float4*)sp;
        float4 s1 = *(const float4*)(sp + 4);
        float2 s2 = *(const float2*)(sp + 8);
        float p = ph[j];
        eacc[0] += p * s0.x; eacc[1] += p * s0.y; eacc[2] += p * s0.z; eacc[3] += p * s0.w;
        eacc[4] += p * s1.x; eacc[5] += p * s1.y; eacc[6] += p * s1.z; eacc[7] += p * s1.w;
        eacc[8] += p * s2.x; eacc[9] += p * s2.y;
      }
    }
    #pragma unroll
    for (int o = 0; o < 10; ++o) atomicAdd(&sm[LEL + t2 * 12 + o], eacc[o]);
  }
  if (t < 256) sm[LEL + t2 * 12 + 10] = ug;   // slot 10: no overlap with atomics
  __syncthreads();                                   // (5) E+u final; m ready
  // P5: a_un = W1 m (4-way g-split, bf16 16B row gathers); C (4 chunks x 100)
  {
    int r = t & 127, c4 = t >> 7;   // 0..3
    int ga0 = c4 * 64;
    float ap = 0.f;
    for (int g = ga0; g < ga0 + 64; g += 8) {
      float wv[8];
      ld8v<BF>(W1in, r * 256 + g, wv);
      ap += wv[0] * sm[LM + g]     + wv[1] * sm[LM + g + 1]
          + wv[2] * sm[LM + g + 2] + wv[3] * sm[LM + g + 3]
          + wv[4] * sm[LM + g + 4] + wv[5] * sm[LM + g + 5]
          + wv[6] * sm[LM + g + 6] + wv[7] * sm[LM + g + 7];
    }
    atomicAdd(&sm[LAUN + r], ap);
  }
  if (t < 400) {
    int chk = t / 100, idx = t - chk * 100;
    int o = idx / 10, p = idx - o * 10;
    int gc0 = chk * 64;
    float cp = 0.f;
    #pragma unroll 4
    for (int g = gc0; g < gc0 + 64; ++g)
      cp += sm[LSW2 + g * 12 + o] * sm[LEL + g * 12 + p];
    atomicAdd(&sm[LCL + idx], cp);
  }
  __syncthreads();                                   // (6)
  // P6: CW row + E row to regs; F^2 over own 32-row half of the band
  float cwr[10], er[10], uc;
  #pragma unroll
  for (int o = 0; o < 10; ++o) {
    float cw = 0.f;
    #pragma unroll
    for (int p = 0; p < 10; ++p) cw += sm[LCL + o * 10 + p] * w2r[p];
    cwr[o] = cw;
  }
  {
    const float* ep = &sm[LEL + t2 * 12];
    float4 e0 = *(const float4*)ep;
    float4 e1 = *(const float4*)(ep + 4);
    float4 e2 = *(const float4*)(ep + 8);
    er[0]=e0.x; er[1]=e0.y; er[2]=e0.z; er[3]=e0.w;
    er[4]=e1.x; er[5]=e1.y; er[6]=e1.z; er[7]=e1.w;
    er[8]=e2.x; er[9]=e2.y; uc = e2.z;
  }
  int band = (t2 >> 6) * 64 + q * 32;
  float acc = 0.f;
  for (int i0 = 0; i0 < 32; i0 += 16) {
    float ph[16];
    #pragma unroll
    for (int j = 0; j < 16; ++j)
      ph[j] = ws[OP + (band + i0 + j) * 256 + t2];   // 16 loads in flight
    #pragma unroll
    for (int j = 0; j < 16; ++j) {
      int h = band + i0 + j;
      const float* rp = &sm[LEL + h * 12];
      float4 E0 = *(const float4*)rp;
      float4 E1 = *(const float4*)(rp + 4);
      float4 E2 = *(const float4*)(rp + 8);     // E8,E9,u,0
      const float* wpp = &sm[LW2P + h * 12];
      float4 W0 = *(const float4*)wpp;
      float4 W1v = *(const float4*)(wpp + 4);
      float4 W2v = *(const float4*)(wpp + 8);   // W8,W9,0,0
      float R = E0.x*w2r[0] + E0.y*w2r[1] + E0.z*w2r[2] + E0.w*w2r[3]
              + E1.x*w2r[4] + E1.y*w2r[5] + E1.z*w2r[6] + E1.w*w2r[7]
              + E2.x*w2r[8] + E2.y*w2r[9];
      float Rt = W0.x*er[0] + W0.y*er[1] + W0.z*er[2] + W0.w*er[3]
               + W1v.x*er[4] + W1v.y*er[5] + W1v.z*er[6] + W1v.w*er[7]
               + W2v.x*er[8] + W2v.y*er[9];
      float Qd = W0.x*cwr[0] + W0.y*cwr[1] + W0.z*cwr[2] + W0.w*cwr[3]
               + W1v.x*cwr[4] + W1v.y*cwr[5] + W1v.z*cwr[6] + W1v.w*cwr[7]
               + W2v.x*cwr[8] + W2v.y*cwr[9];
      acc += E2.z * ph[j] * (ph[j] * Qd + R * Rt);
    }
  }
  acc *= uc;
  #pragma unroll
  for (int m = 32; m > 0; m >>= 1) acc += __shfl_xor(acc, m);
  if ((t & 63) == 0) sm[LRED + w] = acc;             // LRED[0..7] (y use dead)
  __syncthreads();                                   // (7)
  float F = sqrtf(fmaxf(2.f * (sm[LRED] + sm[LRED+1] + sm[LRED+2] + sm[LRED+3]
                             + sm[LRED+4] + sm[LRED+5] + sm[LRED+6] + sm[LRED+7]), 0.f));
  float denom = (F + 1e-6f) * (sm[LYS + 10] + 1e-6f);
  if (t < 128) {
    st<BF>(out, b * 128 + t, ld<BF>(sbin, (NB + b) * 128 + t));   // dev_velocity
    float dev = ld<BF>(sbin, b * 128 + t);
    float val = -sm[LAUN + t] / denom - 0.1f * dev;
    st<BF>(out, (NB + b) * 128 + t, val);
  }
  __syncthreads();                                   // (8)
  if (t == 0) {
    int old = __hip_atomic_fetch_add(&g_bdone, 1, __ATOMIC_RELAXED, __HIP_MEMORY_SCOPE_AGENT);
    if (old == NB - 1) {   // last batch block: reset flags for next launch
      __hip_atomic_store(&g_pdone, 0, __ATOMIC_RELAXED, __HIP_MEMORY_SCOPE_AGENT);
      __hip_atomic_store(&g_bdone, 0, __ATOMIC_RELAXED, __HIP_MEMORY_SCOPE_AGENT);
    }
  }
}

__global__ __launch_bounds__(512) void FK(const void* tin, const void* sbin,
                                          const void* x0in, const void* x1in,
                                          const void* W1in, const void* b1in,
                                          const void* W2in, void* out, float* ws) {
  __shared__ int sh;
  __shared__ __align__(16) float sm[LTOT];
  int bf = blocksniff(sbin, &sh);
  if (bf) fk_body<1>(tin, sbin, x0in, x1in, W1in, b1in, W2in, out, ws, sm);
  else    fk_body<0>(tin, sbin, x0in, x1in, W1in, b1in, W2in, out, ws, sm);
}

extern "C" void kernel_launch(void* const* d_in, const int* in_sizes, int n_in,
                              void* d_out, int out_size, void* d_ws, size_t ws_size,
                              hipStream_t stream) {
  float* ws = (float*)d_ws;
  const void* tin  = d_in[0];
  const void* sbin = d_in[1];
  const void* x0in = d_in[2];
  const void* x1in = d_in[3];
  const void* W1in = d_in[4];
  const void* b1in = d_in[5];
  const void* W2in = d_in[6];
  // d_in[7] (b2) cancels in every derivative.

  FK<<<dim3(NB + NH), dim3(512), 0, stream>>>(tin, sbin, x0in, x1in, W1in, b1in, W2in, d_out, ws);
}

// Round 8
// 90.879 us; speedup vs baseline: 1.1251x; 1.1082x over previous
//
#include <hip/hip_runtime.h>
#include <hip/hip_bf16.h>

// B=32, D=128, H=256, O=10.
// s = 1-tanh(W1^T x + b1)^2, u = -2 z s, P = W1^T W1 (HxH).
// Rank-10 structure (M = W2 W2^T):
//   sw2[g,o] = s_g W2[g,o]; F1 = W1 sw2 (128x10); E = W1^T F1 (256x10)
//   y_o = sum_h W2[h,o] u_h w_h^2  (w = W1^T v)
//   a_un = W1 (s o (W2 y)) = F1 y
//   C[o,p] = sum_g sw2[g,o] E[g,p] (10x10), CW = C W2^T
//   F^2 = 2 sum u_h u_h' (P^2 o Q + P o R o R^T)   (same band structure as
//     all verified rounds; only fp32 summation order changes here)
//   a_i = -a_un[i]/((F+1e-6)(||v||+1e-6))
// Round-8: VERBATIM revert to the round-5 kernel (measured 91.6 us, session
// best). Round-6 (E=P.sw2 @1024thr) regressed via launch_bounds VGPR-64
// spills; round-7 (E=P.sw2 @512thr) regressed via 8MB of extra P traffic +
// early helper-spin serialization. The F1-from-W1 route keeps the batch
// pipeline independent of P until F^2, hiding all helper latency.
// Structure: 512-thread batch blocks (8 waves = 2/SIMD), phases split across
// waves; helpers 128 blocks x 512 thr, 2 P rows each. Fence-free
// relaxed-atomic handoff (sc1 stores -> coherent point; RELAXED flag after
// vmcnt-drain; RELAXED spin; plain consumer loads).

#define NB 32
#define OP 0        // ws: P [h*256+g], 65536 floats

__device__ int g_pdone = 0;
__device__ int g_bdone = 0;

template<int BF> __device__ __forceinline__ float ld(const void* p, int i) {
  if constexpr (BF) return __bfloat162float(((const __hip_bfloat16*)p)[i]);
  else return ((const float*)p)[i];
}
template<int BF> __device__ __forceinline__ void st(void* p, int i, float v) {
  if constexpr (BF) ((__hip_bfloat16*)p)[i] = __float2bfloat16(v);
  else ((float*)p)[i] = v;
}
__device__ __forceinline__ float b2f(unsigned short u) {
  return __uint_as_float(((unsigned int)u) << 16);
}
// 8 consecutive elements, idx %8==0 (BF path: one 16B uint4 load)
template<int BF> __device__ __forceinline__ void ld8v(const void* p, int i, float* o) {
  if constexpr (BF) {
    uint4 u = *(const uint4*)((const unsigned short*)p + i);
    o[0] = b2f((unsigned short)(u.x & 0xffff)); o[1] = b2f((unsigned short)(u.x >> 16));
    o[2] = b2f((unsigned short)(u.y & 0xffff)); o[3] = b2f((unsigned short)(u.y >> 16));
    o[4] = b2f((unsigned short)(u.z & 0xffff)); o[5] = b2f((unsigned short)(u.z >> 16));
    o[6] = b2f((unsigned short)(u.w & 0xffff)); o[7] = b2f((unsigned short)(u.w >> 16));
  } else {
    float4 a = *(const float4*)((const float*)p + i);
    float4 b = *(const float4*)((const float*)p + i + 4);
    o[0]=a.x; o[1]=a.y; o[2]=a.z; o[3]=a.w; o[4]=b.x; o[5]=b.y; o[6]=b.z; o[7]=b.w;
  }
}

// dtype sniff: view first 256 half-words of state_batch as bf16. fp32 storage
// puts random-exponent garbage in the low halves -> some |v|>1000 w.p. ~1.
__device__ __forceinline__ int blocksniff(const void* sb, int* sh) {
  if (threadIdx.x == 0) *sh = 0;
  __syncthreads();
  float v = fabsf(__bfloat162float(((const __hip_bfloat16*)sb)[threadIdx.x & 255]));
  if (!(v < 1000.0f)) atomicOr(sh, 1);
  __syncthreads();
  return (*sh == 0) ? 1 : 0;
}

// LDS carve (floats), total 14592 = 58.4 KB (<64KB static cap).
// Region reuse: F1 quarter-partials live in LEL (+0,+1536) and LW2P (+0)
// before those regions' real contents exist; E q=1 partials in LW2P; the
// padded-W2 copy into LW2P is deferred until after the E combine.
#define LXS   0       // 128
#define LVS   128     // 128
#define LW2   256     // 2560 raw W2 (stride 10)
#define LYS   2816    // 16: [0..9]=y, [10]=||v||
#define LRED  2832    // 96: 8 waves * 12 (y phase); [0..7] reused for F^2
#define LHW   2928    // 512: q=1 h/w partials
#define LF1   3440    // 1536: 128*12
#define LEL   4976    // 3072: final [0..9]=E,[10]=u; earlier F1 partials q1/q2
#define LSW2  8048    // 3072
#define LCL   11120   // 100
#define LCQ   11220   // 300: C chunk partials
#define LW2P  11520   // 3072: F1 q3 partial -> E q=1 partial -> padded W2
#define LTOT  14592

#define F1ACC(wv, gidx) do { \
    const float* sp_ = &sm[LSW2 + (gidx)*12]; \
    float4 s0_ = *(const float4*)sp_; \
    float4 s1_ = *(const float4*)(sp_+4); \
    float2 s2_ = *(const float2*)(sp_+8); \
    fa[0]+=(wv)*s0_.x; fa[1]+=(wv)*s0_.y; fa[2]+=(wv)*s0_.z; fa[3]+=(wv)*s0_.w; \
    fa[4]+=(wv)*s1_.x; fa[5]+=(wv)*s1_.y; fa[6]+=(wv)*s1_.z; fa[7]+=(wv)*s1_.w; \
    fa[8]+=(wv)*s2_.x; fa[9]+=(wv)*s2_.y; \
  } while (0)

template<int BF>
__device__ void fk_body(const void* tin, const void* sbin, const void* x0in,
                        const void* x1in, const void* W1in, const void* b1in,
                        const void* W2in, void* out, float* ws, float* sm) {
  int bid = blockIdx.x, t = threadIdx.x;
  if (bid >= NB) {
    // ---- helper block: 2 P rows (row0, row0+1) ----
    int row0 = (bid - NB) * 2;
    float* colh = sm;            // 256: two W1 columns
    if (t < 256) {
      int qq = t >> 7, d = t & 127;
      colh[qq * 128 + d] = ld<BF>(W1in, d * 256 + row0 + qq);
    }
    __syncthreads();
    int q = t >> 8, c = t & 255;
    const float* ch = &colh[q * 128];
    float pacc = 0.f;
    for (int d = 0; d < 128; d += 4) {
      float4 c4 = *(const float4*)&ch[d];
      pacc += c4.x * ld<BF>(W1in, (d + 0) * 256 + c);
      pacc += c4.y * ld<BF>(W1in, (d + 1) * 256 + c);
      pacc += c4.z * ld<BF>(W1in, (d + 2) * 256 + c);
      pacc += c4.w * ld<BF>(W1in, (d + 3) * 256 + c);
    }
    // coherent (sc1) store: visible at device coherent point, no dirty L2 line
    __hip_atomic_store(&ws[OP + (row0 + q) * 256 + c], pacc,
                       __ATOMIC_RELAXED, __HIP_MEMORY_SCOPE_AGENT);
    __syncthreads();   // drains vmcnt(0): all 512 coherent stores ack'd
    if (t == 0)
      __hip_atomic_fetch_add(&g_pdone, 1, __ATOMIC_RELAXED, __HIP_MEMORY_SCOPE_AGENT);
    return;
  }
  // ---- batch block b (512 threads, 8 waves) ----
  int b = bid;
  int t2 = t & 255;          // h / column index
  int q  = t >> 8;           // 0/1 half
  int w  = t >> 6;           // wave 0..7
  int r  = t & 127;          // F1 row
  int qr = t >> 7;           // F1 g-quarter 0..3
  float tt = ld<BF>(tin, 0);
  float window = 4.f * tt * (1.f - tt);
  if (t < 128) {
    float dev = ld<BF>(sbin, b * 128 + t);
    float v   = ld<BF>(sbin, (NB + b) * 128 + t);
    float x0v = ld<BF>(x0in, b * 128 + t);
    float x1v = ld<BF>(x1in, b * 128 + t);
    sm[LXS + t] = x0v + tt * (x1v - x0v) + window * dev;
    sm[LVS + t] = v;
  }
  for (int i = t; i < 2560; i += 512) sm[LW2 + i] = ld<BF>(W2in, i);
  __syncthreads();                                   // (1)
  // h, w projection partials over own d-half (coalesced column reads)
  float hp = q ? 0.f : ld<BF>(b1in, t2), wp = 0.f;
  {
    int d0 = q * 64;
    for (int d = d0; d < d0 + 64; d += 4) {
      float4 xv = *(const float4*)&sm[LXS + d];
      float4 vv = *(const float4*)&sm[LVS + d];
      float w0 = ld<BF>(W1in, (d + 0) * 256 + t2);
      float w1 = ld<BF>(W1in, (d + 1) * 256 + t2);
      float w2 = ld<BF>(W1in, (d + 2) * 256 + t2);
      float w3 = ld<BF>(W1in, (d + 3) * 256 + t2);
      hp += w0 * xv.x + w1 * xv.y + w2 * xv.z + w3 * xv.w;
      wp += w0 * vv.x + w1 * vv.y + w2 * vv.z + w3 * vv.w;
    }
  }
  if (q) { sm[LHW + t2 * 2] = hp; sm[LHW + t2 * 2 + 1] = wp; }
  float w2r[10];
  #pragma unroll
  for (int o = 0; o < 10; ++o) w2r[o] = sm[LW2 + t2 * 10 + o];
  __syncthreads();                                   // (2)
  float ug = 0.f;
  if (!q) {     // combine halves, activation, sw2 row, y/||v|| reduction
    float hacc = hp + sm[LHW + t2 * 2];
    float wacc = wp + sm[LHW + t2 * 2 + 1];
    float z  = tanhf(hacc);
    float sg = 1.f - z * z;
    ug = -2.f * z * sg;
    #pragma unroll
    for (int o = 0; o < 10; ++o) sm[LSW2 + t2 * 12 + o] = sg * w2r[o];
    float cval = ug * wacc * wacc;
    float rv[11];
    #pragma unroll
    for (int o = 0; o < 10; ++o) rv[o] = cval * w2r[o];
    rv[10] = (t < 128) ? sm[LVS + t] * sm[LVS + t] : 0.f;
    #pragma unroll
    for (int o = 0; o < 11; ++o) {
      float v = rv[o];
      #pragma unroll
      for (int m = 32; m > 0; m >>= 1) v += __shfl_xor(v, m);
      if ((t & 63) == 0) sm[LRED + w * 12 + o] = v;
    }
  }
  __syncthreads();                                   // (3)
  if (t < 11) {
    float s = sm[LRED + t] + sm[LRED + 12 + t] + sm[LRED + 24 + t] + sm[LRED + 36 + t];
    if (t < 10) sm[LYS + t] = s;
    else        sm[LYS + 10] = sqrtf(s);
  }
  // F1[r,o] = sum_g W1[r,g] sw2[g,o]; 4-way g-split (64 g per thread)
  float fa[10];
  #pragma unroll
  for (int o = 0; o < 10; ++o) fa[o] = 0.f;
  {
    int gbase = qr * 64;
    for (int gg = 0; gg < 64; gg += 8) {
      int g = gbase + gg;
      float wv[8];
      ld8v<BF>(W1in, r * 256 + g, wv);   // contiguous 16B row gather
      F1ACC(wv[0], g + 0); F1ACC(wv[1], g + 1);
      F1ACC(wv[2], g + 2); F1ACC(wv[3], g + 3);
      F1ACC(wv[4], g + 4); F1ACC(wv[5], g + 5);
      F1ACC(wv[6], g + 6); F1ACC(wv[7], g + 7);
    }
  }
  if (qr == 1) {
    #pragma unroll
    for (int o = 0; o < 10; ++o) sm[LEL + r * 12 + o] = fa[o];
  } else if (qr == 2) {
    #pragma unroll
    for (int o = 0; o < 10; ++o) sm[LEL + 1536 + r * 12 + o] = fa[o];
  } else if (qr == 3) {
    #pragma unroll
    for (int o = 0; o < 10; ++o) sm[LW2P + r * 12 + o] = fa[o];
  }
  __syncthreads();                                   // (4)
  float aun = 0.f;
  if (!qr) {   // t<128: combine quarters, finalize F1 row, a_un = F1 . y
    #pragma unroll
    for (int o = 0; o < 10; ++o) {
      float f = fa[o] + sm[LEL + r * 12 + o] + sm[LEL + 1536 + r * 12 + o]
                      + sm[LW2P + r * 12 + o];
      sm[LF1 + r * 12 + o] = f;
      aun += f * sm[LYS + o];
    }
  }
  __syncthreads();                                   // (5)
  // E[t2,o] = sum_d W1[d,t2] F1[d,o]; 2-way d-split
  float er[10];
  #pragma unroll
  for (int o = 0; o < 10; ++o) er[o] = 0.f;
  {
    int d0 = q * 64;
    for (int d = d0; d < d0 + 64; ++d) {
      float w1v = ld<BF>(W1in, d * 256 + t2);   // coalesced
      const float* fp = &sm[LF1 + d * 12];
      float4 a0 = *(const float4*)fp;
      float4 a1 = *(const float4*)(fp + 4);
      float2 a2 = *(const float2*)(fp + 8);
      er[0] += w1v * a0.x; er[1] += w1v * a0.y; er[2] += w1v * a0.z; er[3] += w1v * a0.w;
      er[4] += w1v * a1.x; er[5] += w1v * a1.y; er[6] += w1v * a1.z; er[7] += w1v * a1.w;
      er[8] += w1v * a2.x; er[9] += w1v * a2.y;
    }
  }
  if (q) {
    #pragma unroll
    for (int o = 0; o < 10; ++o) sm[LW2P + t2 * 12 + o] = er[o];
  }
  __syncthreads();                                   // (6)
  if (!q) {
    #pragma unroll
    for (int o = 0; o < 10; ++o)
      sm[LEL + t2 * 12 + o] = er[o] + sm[LW2P + t2 * 12 + o];
    sm[LEL + t2 * 12 + 10] = ug;
    sm[LEL + t2 * 12 + 11] = 0.f;
  }
  __syncthreads();                                   // (7) E+u final; W2P dead
  // padded W2 copy (deferred; region free now)
  for (int i = t; i < 3072; i += 512) {
    int rr = i / 12, cc = i - rr * 12;
    sm[LW2P + i] = (cc < 10) ? sm[LW2 + rr * 10 + cc] : 0.f;
  }
  // C[o,p] = sum_g sw2[g,o] E[g,p]; 4 g-chunks x 100 threads
  float cpart = 0.f;
  if (t < 400) {
    int chk = t / 100, idx = t - chk * 100;
    int o = idx / 10, p = idx - o * 10;
    const float* sa = &sm[LSW2 + o];
    const float* sb = &sm[LEL + p];
    int g0 = chk * 64;
    #pragma unroll 4
    for (int g = g0; g < g0 + 64; ++g) cpart += sa[g * 12] * sb[g * 12];
    if (chk) sm[LCQ + (chk - 1) * 100 + idx] = cpart;
  }
  __syncthreads();                                   // (8) also covers W2P copy
  if (t < 100)
    sm[LCL + t] = cpart + sm[LCQ + t] + sm[LCQ + 100 + t] + sm[LCQ + 200 + t];
  __syncthreads();                                   // (9)
  // per-column registers for F^2: CW row, full E row, u_c
  float cwr[10];
  #pragma unroll
  for (int o = 0; o < 10; ++o) {
    float cw = 0.f;
    #pragma unroll
    for (int p = 0; p < 10; ++p) cw += sm[LCL + o * 10 + p] * w2r[p];
    cwr[o] = cw;
  }
  float uc;
  {
    const float* ep = &sm[LEL + t2 * 12];
    float4 e0 = *(const float4*)ep;
    float4 e1 = *(const float4*)(ep + 4);
    float4 e2 = *(const float4*)(ep + 8);
    er[0]=e0.x; er[1]=e0.y; er[2]=e0.z; er[3]=e0.w;
    er[4]=e1.x; er[5]=e1.y; er[6]=e1.z; er[7]=e1.w;
    er[8]=e2.x; er[9]=e2.y; uc = e2.z;
  }
  // ---- wait for P: RELAXED spin, no cache-maintenance ops ----
  if (t == 0) {
    while (__hip_atomic_load(&g_pdone, __ATOMIC_RELAXED, __HIP_MEMORY_SCOPE_AGENT) < 128)
      __builtin_amdgcn_s_sleep(2);
  }
  __syncthreads();                                   // (10)
  // ---- F^2: own column c=t2, own 32-row half of the 64-row band ----
  int band = (t2 >> 6) * 64 + q * 32;
  float acc = 0.f;
  for (int i0 = 0; i0 < 32; i0 += 16) {
    float ph[16];
    #pragma unroll
    for (int j = 0; j < 16; ++j)
      ph[j] = ws[OP + (band + i0 + j) * 256 + t2];   // 16 loads in flight
    #pragma unroll
    for (int j = 0; j < 16; ++j) {
      int h = band + i0 + j;
      const float* rp = &sm[LEL + h * 12];
      float4 E0 = *(const float4*)rp;
      float4 E1 = *(const float4*)(rp + 4);
      float4 E2 = *(const float4*)(rp + 8);     // E8,E9,u,0
      const float* wpp = &sm[LW2P + h * 12];
      float4 W0 = *(const float4*)wpp;
      float4 W1v = *(const float4*)(wpp + 4);
      float4 W2v = *(const float4*)(wpp + 8);   // W8,W9,0,0
      float R = E0.x*w2r[0] + E0.y*w2r[1] + E0.z*w2r[2] + E0.w*w2r[3]
              + E1.x*w2r[4] + E1.y*w2r[5] + E1.z*w2r[6] + E1.w*w2r[7]
              + E2.x*w2r[8] + E2.y*w2r[9];
      float Rt = W0.x*er[0] + W0.y*er[1] + W0.z*er[2] + W0.w*er[3]
               + W1v.x*er[4] + W1v.y*er[5] + W1v.z*er[6] + W1v.w*er[7]
               + W2v.x*er[8] + W2v.y*er[9];
      float Qd = W0.x*cwr[0] + W0.y*cwr[1] + W0.z*cwr[2] + W0.w*cwr[3]
               + W1v.x*cwr[4] + W1v.y*cwr[5] + W1v.z*cwr[6] + W1v.w*cwr[7]
               + W2v.x*cwr[8] + W2v.y*cwr[9];
      acc += E2.z * ph[j] * (ph[j] * Qd + R * Rt);
    }
  }
  acc *= uc;
  #pragma unroll
  for (int m = 32; m > 0; m >>= 1) acc += __shfl_xor(acc, m);
  if ((t & 63) == 0) sm[LRED + w] = acc;             // LRED[0..7] (y use dead)
  __syncthreads();                                   // (11)
  float F = sqrtf(fmaxf(2.f * (sm[LRED] + sm[LRED+1] + sm[LRED+2] + sm[LRED+3]
                             + sm[LRED+4] + sm[LRED+5] + sm[LRED+6] + sm[LRED+7]), 0.f));
  float denom = (F + 1e-6f) * (sm[LYS + 10] + 1e-6f);
  if (t < 128) {   // these are !qr threads: they hold aun
    st<BF>(out, b * 128 + t, ld<BF>(sbin, (NB + b) * 128 + t));   // dev_velocity
    float dev = ld<BF>(sbin, b * 128 + t);
    float val = -aun / denom - 0.1f * dev;
    st<BF>(out, (NB + b) * 128 + t, val);
  }
  __syncthreads();                                   // (12)
  if (t == 0) {
    int old = __hip_atomic_fetch_add(&g_bdone, 1, __ATOMIC_RELAXED, __HIP_MEMORY_SCOPE_AGENT);
    if (old == NB - 1) {   // last batch block: reset flags for next launch
      __hip_atomic_store(&g_pdone, 0, __ATOMIC_RELAXED, __HIP_MEMORY_SCOPE_AGENT);
      __hip_atomic_store(&g_bdone, 0, __ATOMIC_RELAXED, __HIP_MEMORY_SCOPE_AGENT);
    }
  }
}

__global__ __launch_bounds__(512) void FK(const void* tin, const void* sbin,
                                          const void* x0in, const void* x1in,
                                          const void* W1in, const void* b1in,
                                          const void* W2in, void* out, float* ws) {
  __shared__ int sh;
  __shared__ __align__(16) float sm[LTOT];
  int bf = blocksniff(sbin, &sh);
  if (bf) fk_body<1>(tin, sbin, x0in, x1in, W1in, b1in, W2in, out, ws, sm);
  else    fk_body<0>(tin, sbin, x0in, x1in, W1in, b1in, W2in, out, ws, sm);
}

extern "C" void kernel_launch(void* const* d_in, const int* in_sizes, int n_in,
                              void* d_out, int out_size, void* d_ws, size_t ws_size,
                              hipStream_t stream) {
  float* ws = (float*)d_ws;
  const void* tin  = d_in[0];
  const void* sbin = d_in[1];
  const void* x0in = d_in[2];
  const void* x1in = d_in[3];
  const void* W1in = d_in[4];
  const void* b1in = d_in[5];
  const void* W2in = d_in[6];
  // d_in[7] (b2) cancels in every derivative.

  FK<<<dim3(NB + 128), dim3(512), 0, stream>>>(tin, sbin, x0in, x1in, W1in, b1in, W2in, d_out, ws);
}